// Round 8
// baseline (646.526 us; speedup 1.0000x reference)
//
#include <hip/hip_runtime.h>
#include <cmath>

#define NB     8
#define NVERT  14062
#define NV3    42186      // NVERT*3
#define BATCH  256
#define BBLK   16         // batches per block (all threads compute all 16)
#define NBT    16
#define KP     63         // P rows used (bones 1..7, 9 each)
#define KE     55         // E rows
#define KTOT   118        // real K
#define KPAD   120        // FMA'd rows (118..119 have zero coef)
#define KALLOC 128        // allocated coef rows (pipeline over-reads to 122)
#define VBLK   256        // vertices per block (4 waves x 64)
#define NVB    56         // ceil(NVERT/VBLK)

// ---------------- Kernel 1: per-batch setup ----------------
__device__ inline void mat4mul(const float* A, const float* B, float* C) {
#pragma unroll
  for (int i = 0; i < 4; i++)
#pragma unroll
    for (int j = 0; j < 4; j++) {
      float s = 0.f;
#pragma unroll
      for (int k = 0; k < 4; k++) s = fmaf(A[i*4+k], B[k*4+j], s);
      C[i*4+j] = s;
    }
}

__global__ void setup_kernel(const float* __restrict__ theta,  // [256][8][3]
                             const float* __restrict__ bsw,    // [256][55]
                             const float* __restrict__ L2P,    // [8][4][4]
                             float* __restrict__ coef_t,       // [128][256]
                             float* __restrict__ mats)         // [256][8][12]
{
  int b = blockIdx.x * blockDim.x + threadIdx.x;
  if (b >= BATCH) return;

  float R[NB][9];
#pragma unroll
  for (int n = 0; n < NB; n++) {
    float rx = theta[(b*NB+n)*3+0];
    float ry = theta[(b*NB+n)*3+1];
    float rz = theta[(b*NB+n)*3+2];
    float ang = sqrtf(rx*rx + ry*ry + rz*rz + 1e-12f);
    float kx = rx/ang, ky = ry/ang, kz = rz/ang;
    float s = sinf(ang), c = cosf(ang);
    float K[9] = {0.f,-kz,ky,  kz,0.f,-kx,  -ky,kx,0.f};
    float K2[9];
#pragma unroll
    for (int i = 0; i < 3; i++)
#pragma unroll
      for (int j = 0; j < 3; j++) {
        float v = 0.f;
#pragma unroll
        for (int k = 0; k < 3; k++) v = fmaf(K[i*3+k], K[k*3+j], v);
        K2[i*3+j] = v;
      }
#pragma unroll
    for (int e = 0; e < 9; e++) {
      int i = e/3, j = e%3;
      R[n][e] = (i==j ? 1.f : 0.f) + s*K[e] + (1.f-c)*K2[e];
    }
  }

  // coef rows 0..62: theta_zero for bones 1..7 (bone 0 row is exactly zero)
#pragma unroll
  for (int n = 1; n < NB; n++)
#pragma unroll
    for (int e = 0; e < 9; e++) {
      int i = e/3, j = e%3;
      coef_t[((n-1)*9+e)*BATCH + b] = R[n][e] - (i==j ? 1.f : 0.f);
    }
  // rows 63..117: bsw
  for (int s2 = 0; s2 < KE; s2++)
    coef_t[(KP+s2)*BATCH + b] = bsw[b*KE + s2];
  // rows 118..127: zero padding (pipeline over-reads)
  for (int r = KTOT; r < KALLOC; r++)
    coef_t[(size_t)r*BATCH + b] = 0.f;

  // FK chain + rest chain + rigid inverse + skin matrices
  float prevPose[16], prevRest[16];
#pragma unroll 1
  for (int n = 0; n < NB; n++) {
    float loc[16] = {R[n][0],R[n][1],R[n][2],0.f,
                     R[n][3],R[n][4],R[n][5],0.f,
                     R[n][6],R[n][7],R[n][8],0.f,
                     0.f,0.f,0.f,1.f};
    float A[16], pose[16], rest[16];
    mat4mul(&L2P[n*16], loc, A);
    if (n == 0) {
#pragma unroll
      for (int q = 0; q < 16; q++) { pose[q] = A[q]; rest[q] = L2P[q]; }
    } else {
      mat4mul(prevPose, A, pose);
      mat4mul(prevRest, &L2P[n*16], rest);
    }
    float w2l[16];
#pragma unroll
    for (int i = 0; i < 3; i++) {
#pragma unroll
      for (int j = 0; j < 3; j++) w2l[i*4+j] = rest[j*4+i];
      w2l[i*4+3] = -(rest[0*4+i]*rest[0*4+3] + rest[1*4+i]*rest[1*4+3] + rest[2*4+i]*rest[2*4+3]);
    }
    w2l[12]=0.f; w2l[13]=0.f; w2l[14]=0.f; w2l[15]=1.f;
    float skin[16];
    mat4mul(pose, w2l, skin);
#pragma unroll
    for (int i = 0; i < 3; i++)
#pragma unroll
      for (int j = 0; j < 4; j++)
        mats[(size_t)b*96 + n*12 + i*4 + j] = skin[i*4+j];
#pragma unroll
    for (int q = 0; q < 16; q++) { prevPose[q] = pose[q]; prevRest[q] = rest[q]; }
  }
}

// ---------------- Kernel 2: fused GEMM + bilinear + LBS ----------------
// 256 threads = 4 waves; wave wv owns vertices vbase+wv*64+lane (disjoint —
// no redundant D traffic). Block covers 16 batches; coef staged in LDS once;
// K-loop is barrier-free with a depth-2 register pipeline on the D loads.
__global__ __launch_bounds__(256, 4) void fused_kernel(
    const float* __restrict__ P, const float* __restrict__ E,
    const float* __restrict__ coef_t, const float* __restrict__ matsg,
    const float* __restrict__ Wm, const float* __restrict__ T,
    const float* __restrict__ ts, const float* __restrict__ uvgrid,
    const float* __restrict__ Limg, const float* __restrict__ tau,
    const float* __restrict__ alpha, float* __restrict__ out)
{
  // XCD swizzle: bid%8 == y%8 so all 16 batch-groups of a vertex-block land
  // on one XCD (per-XCD D slice = 7 vblocks x 118 x 3KB = 2.5MB < 4MB L2).
  int bid = blockIdx.x;
  int r  = bid & 7;
  int t  = bid >> 3;            // 0..111
  int x  = t & 15;              // batch-group 0..15
  int y  = ((t >> 4) << 3) | r; // vertex-block 0..55
  if (y * VBLK >= NVERT) return;   // uniform early-exit (before barrier)

  __shared__ float clds[KALLOC][NBT];   // 8 KB coef tile
  __shared__ float mlds[NBT][96];       // 6 KB skin mats
  __shared__ float ta_s[NBT], al_s[NBT];

  int tid  = threadIdx.x;
  int lane = tid & 63;
  int wv   = tid >> 6;               // 0..3
  int bbase = x * BBLK;
  int vbase = y * VBLK;
  int v = vbase + wv*64 + lane;
  bool vok = v < NVERT;
  int vc = vok ? v : NVERT - 1;
  int voffi = vc * 3;

  // stage coef: 128 rows x 16 batches = 512 float4, 2 per thread
#pragma unroll
  for (int rep = 0; rep < 2; rep++) {
    int q = tid + rep*256;           // float4 index 0..511
    int row = q >> 2, i4 = q & 3;
    *reinterpret_cast<float4*>(&clds[row][i4*4]) =
        *reinterpret_cast<const float4*>(coef_t + (size_t)row*BATCH + bbase + i4*4);
  }
  // stage mats: 16 x 96 floats = 384 float4
  {
    int q = tid;                     // 0..255
    int bb = q / 24, chunk = q - bb*24;
    *reinterpret_cast<float4*>(&mlds[bb][chunk*4]) =
        *reinterpret_cast<const float4*>(matsg + (size_t)(bbase+bb)*96 + chunk*4);
    q = tid + 256;
    if (q < 384) {
      bb = q / 24; chunk = q - bb*24;
      *reinterpret_cast<float4*>(&mlds[bb][chunk*4]) =
          *reinterpret_cast<const float4*>(matsg + (size_t)(bbase+bb)*96 + chunk*4);
    }
  }
  if (tid < NBT) { ta_s[tid] = tau[bbase+tid]; al_s[tid] = alpha[bbase+tid]; }
  __syncthreads();   // the ONLY barrier

  const float* Pb = P + (size_t)9 * NV3;   // row c<63 -> Pb + c*NV3

  float acc[NBT][3];
#pragma unroll
  for (int j = 0; j < NBT; j++) { acc[j][0]=0.f; acc[j][1]=0.f; acc[j][2]=0.f; }

  // three pipeline row-sets -> depth-2 prefetch (D from global, coef from LDS)
  float dA0,dA1,dA2, dB0,dB1,dB2, dC0,dC1,dC2;
  float4 cA0,cA1,cA2,cA3, cB0,cB1,cB2,cB3, cC0,cC1,cC2,cC3;

#define LOAD_ROW(cn, D0,D1,D2, C0,C1,C2,C3)                              \
  {                                                                      \
    int cd = (cn) <= (KTOT-1) ? (cn) : (KTOT-1);                         \
    const float* rp = (cd < KP) ? (Pb + (size_t)cd*NV3)                  \
                                : (E + (size_t)(cd-KP)*NV3);             \
    D0 = rp[voffi+0]; D1 = rp[voffi+1]; D2 = rp[voffi+2];                \
    const float* cp = &clds[(cn)][0];                                    \
    C0 = *reinterpret_cast<const float4*>(cp+0);                         \
    C1 = *reinterpret_cast<const float4*>(cp+4);                         \
    C2 = *reinterpret_cast<const float4*>(cp+8);                         \
    C3 = *reinterpret_cast<const float4*>(cp+12);                        \
  }

#define FMA_ROW(D0,D1,D2, C0,C1,C2,C3)                                   \
  {                                                                      \
    float cf[NBT] = {C0.x,C0.y,C0.z,C0.w, C1.x,C1.y,C1.z,C1.w,           \
                     C2.x,C2.y,C2.z,C2.w, C3.x,C3.y,C3.z,C3.w};          \
    _Pragma("unroll")                                                    \
    for (int j = 0; j < NBT; j++) {                                      \
      acc[j][0] = fmaf(cf[j], D0, acc[j][0]);                            \
      acc[j][1] = fmaf(cf[j], D1, acc[j][1]);                            \
      acc[j][2] = fmaf(cf[j], D2, acc[j][2]);                            \
    }                                                                    \
  }

  LOAD_ROW(0, dA0,dA1,dA2, cA0,cA1,cA2,cA3);
  LOAD_ROW(1, dB0,dB1,dB2, cB0,cB1,cB2,cB3);
  LOAD_ROW(2, dC0,dC1,dC2, cC0,cC1,cC2,cC3);

#pragma unroll 1
  for (int c = 0; c < KPAD; c += 3) {
    FMA_ROW(dA0,dA1,dA2, cA0,cA1,cA2,cA3);
    LOAD_ROW(c+3, dA0,dA1,dA2, cA0,cA1,cA2,cA3);
    FMA_ROW(dB0,dB1,dB2, cB0,cB1,cB2,cB3);
    LOAD_ROW(c+4, dB0,dB1,dB2, cB0,cB1,cB2,cB3);
    FMA_ROW(dC0,dC1,dC2, cC0,cC1,cC2,cC3);
    LOAD_ROW(c+5, dC0,dC1,dC2, cC0,cC1,cC2,cC3);
  }

  // ---------------- fused epilogue (per-vertex lane, 16 batches) ----------
  float W8[NB];
#pragma unroll
  for (int n = 0; n < NB; n++) W8[n] = Wm[(size_t)n*NVERT + vc];
  float T0 = T[vc*3+0], T1 = T[vc*3+1], T2 = T[vc*3+2];
  float s0 = ts[vc*3+0], s1 = ts[vc*3+1], s2 = ts[vc*3+2];
  float u0 = uvgrid[vc*2+0], u1 = uvgrid[vc*2+1];

  float xc = fminf(fmaxf(u0*255.f, 0.f), 255.f);
  float xf = floorf(xc);
  int x0i = (int)xf;
  int x1i = min(x0i+1, 255);
  float wx = xc - xf;

#pragma unroll
  for (int j = 0; j < NBT; j++) {
    float yc = fminf(fmaxf((u1 + ta_s[j])*255.f, 0.f), 255.f);
    float yf = floorf(yc);
    int y0i = (int)yf;
    int y1i = min(y0i+1, 255);
    float wy = yc - yf;
    float v00 = Limg[y0i*256 + x0i], v01 = Limg[y0i*256 + x1i];
    float v10 = Limg[y1i*256 + x0i], v11 = Limg[y1i*256 + x1i];
    float dist = (v00*(1.f-wx) + v01*wx)*(1.f-wy) + (v10*(1.f-wx) + v11*wx)*wy;
    float da = dist * al_s[j];

    float xv0 = acc[j][0] + T0 + da*s0;
    float xv1 = acc[j][1] + T1 + da*s1;
    float xv2 = acc[j][2] + T2 + da*s2;

    float o[3];
#pragma unroll
    for (int i = 0; i < 3; i++) {
      float c0=0.f, c1=0.f, c2=0.f, c3=0.f;
#pragma unroll
      for (int n = 0; n < NB; n++) {
        float4 m = *reinterpret_cast<const float4*>(&mlds[j][n*12 + i*4]);
        float w = W8[n];
        c0 = fmaf(w, m.x, c0); c1 = fmaf(w, m.y, c1);
        c2 = fmaf(w, m.z, c2); c3 = fmaf(w, m.w, c3);
      }
      o[i] = fmaf(c0, xv0, fmaf(c1, xv1, fmaf(c2, xv2, c3)));
    }
    if (vok) {
      size_t off = (size_t)(bbase + j)*NV3 + (size_t)v*3;
      out[off+0] = o[0];
      out[off+1] = o[1];
      out[off+2] = o[2];
    }
  }
}

// ---------------- launcher ----------------
extern "C" void kernel_launch(void* const* d_in, const int* in_sizes, int n_in,
                              void* d_out, int out_size, void* d_ws, size_t ws_size,
                              hipStream_t stream)
{
  const float* theta  = (const float*)d_in[0];
  const float* tau    = (const float*)d_in[1];
  const float* alpha  = (const float*)d_in[2];
  const float* bsw    = (const float*)d_in[3];
  const float* Wm     = (const float*)d_in[4];
  const float* T      = (const float*)d_in[5];
  const float* P      = (const float*)d_in[6];
  const float* L      = (const float*)d_in[7];
  const float* ts     = (const float*)d_in[8];
  const float* L2P    = (const float*)d_in[9];
  const float* E      = (const float*)d_in[10];
  const float* uvgrid = (const float*)d_in[11];
  float* out = (float*)d_out;

  float* coef_t = (float*)d_ws;                     // 128*256 floats
  float* mats   = coef_t + (size_t)KALLOC * BATCH;  // 256*96 floats

  setup_kernel<<<dim3(4), dim3(64), 0, stream>>>(theta, bsw, L2P, coef_t, mats);
  // 896 = 16 batch-groups x 56 vertex-blocks (y=55 exits early)
  fused_kernel<<<dim3(896), dim3(256), 0, stream>>>(
      P, E, coef_t, mats, Wm, T, ts, uvgrid, L, tau, alpha, out);
}

// Round 10
// 183.513 us; speedup vs baseline: 3.5231x; 3.5231x over previous
//
#include <hip/hip_runtime.h>
#include <cmath>

#define NB     8
#define NVERT  14062
#define NV3    42186      // NVERT*3
#define BATCH  256
#define BBLK   16         // batches per block (all threads compute all 16)
#define NBT    16
#define KP     63         // P rows used (bones 1..7, 9 each)
#define KE     55         // E rows
#define KTOT   118        // real K
#define KPAD   120        // FMA'd rows (118..119 have zero coef)
#define KALLOC 128        // allocated coef rows (pipeline over-reads to 122)
#define VBLK   256        // vertices per block (4 waves x 64)

// ---------------- Kernel 1: per-batch setup ----------------
__device__ inline void mat4mul(const float* A, const float* B, float* C) {
#pragma unroll
  for (int i = 0; i < 4; i++)
#pragma unroll
    for (int j = 0; j < 4; j++) {
      float s = 0.f;
#pragma unroll
      for (int k = 0; k < 4; k++) s = fmaf(A[i*4+k], B[k*4+j], s);
      C[i*4+j] = s;
    }
}

__global__ void setup_kernel(const float* __restrict__ theta,  // [256][8][3]
                             const float* __restrict__ bsw,    // [256][55]
                             const float* __restrict__ L2P,    // [8][4][4]
                             float* __restrict__ coef_t,       // [128][256]
                             float* __restrict__ mats)         // [256][8][12]
{
  int b = blockIdx.x * blockDim.x + threadIdx.x;
  if (b >= BATCH) return;

  float R[NB][9];
#pragma unroll
  for (int n = 0; n < NB; n++) {
    float rx = theta[(b*NB+n)*3+0];
    float ry = theta[(b*NB+n)*3+1];
    float rz = theta[(b*NB+n)*3+2];
    float ang = sqrtf(rx*rx + ry*ry + rz*rz + 1e-12f);
    float kx = rx/ang, ky = ry/ang, kz = rz/ang;
    float s = sinf(ang), c = cosf(ang);
    float K[9] = {0.f,-kz,ky,  kz,0.f,-kx,  -ky,kx,0.f};
    float K2[9];
#pragma unroll
    for (int i = 0; i < 3; i++)
#pragma unroll
      for (int j = 0; j < 3; j++) {
        float v = 0.f;
#pragma unroll
        for (int k = 0; k < 3; k++) v = fmaf(K[i*3+k], K[k*3+j], v);
        K2[i*3+j] = v;
      }
#pragma unroll
    for (int e = 0; e < 9; e++) {
      int i = e/3, j = e%3;
      R[n][e] = (i==j ? 1.f : 0.f) + s*K[e] + (1.f-c)*K2[e];
    }
  }

  // coef rows 0..62: theta_zero for bones 1..7 (bone 0 row is exactly zero)
#pragma unroll
  for (int n = 1; n < NB; n++)
#pragma unroll
    for (int e = 0; e < 9; e++) {
      int i = e/3, j = e%3;
      coef_t[((n-1)*9+e)*BATCH + b] = R[n][e] - (i==j ? 1.f : 0.f);
    }
  // rows 63..117: bsw
  for (int s2 = 0; s2 < KE; s2++)
    coef_t[(KP+s2)*BATCH + b] = bsw[b*KE + s2];
  // rows 118..127: zero padding (pipeline over-reads)
  for (int r = KTOT; r < KALLOC; r++)
    coef_t[(size_t)r*BATCH + b] = 0.f;

  // FK chain + rest chain + rigid inverse + skin matrices
  float prevPose[16], prevRest[16];
#pragma unroll 1
  for (int n = 0; n < NB; n++) {
    float loc[16] = {R[n][0],R[n][1],R[n][2],0.f,
                     R[n][3],R[n][4],R[n][5],0.f,
                     R[n][6],R[n][7],R[n][8],0.f,
                     0.f,0.f,0.f,1.f};
    float A[16], pose[16], rest[16];
    mat4mul(&L2P[n*16], loc, A);
    if (n == 0) {
#pragma unroll
      for (int q = 0; q < 16; q++) { pose[q] = A[q]; rest[q] = L2P[q]; }
    } else {
      mat4mul(prevPose, A, pose);
      mat4mul(prevRest, &L2P[n*16], rest);
    }
    float w2l[16];
#pragma unroll
    for (int i = 0; i < 3; i++) {
#pragma unroll
      for (int j = 0; j < 3; j++) w2l[i*4+j] = rest[j*4+i];
      w2l[i*4+3] = -(rest[0*4+i]*rest[0*4+3] + rest[1*4+i]*rest[1*4+3] + rest[2*4+i]*rest[2*4+3]);
    }
    w2l[12]=0.f; w2l[13]=0.f; w2l[14]=0.f; w2l[15]=1.f;
    float skin[16];
    mat4mul(pose, w2l, skin);
#pragma unroll
    for (int i = 0; i < 3; i++)
#pragma unroll
      for (int j = 0; j < 4; j++)
        mats[(size_t)b*96 + n*12 + i*4 + j] = skin[i*4+j];
#pragma unroll
    for (int q = 0; q < 16; q++) { prevPose[q] = pose[q]; prevRest[q] = rest[q]; }
  }
}

// ---------------- Kernel 2: fused GEMM + bilinear + LBS ----------------
// 256 threads = 4 waves; wave wv owns vertices vbase+wv*64+lane (disjoint).
// Block covers 16 batches; coef + mats staged in LDS once (single barrier).
// K-loop: D rows via depth-2 register pipeline (global), coef read at-use
// from LDS (uniform-address broadcast, 4x ds_read_b128 per row).
__global__ __launch_bounds__(256) void fused_kernel(
    const float* __restrict__ P, const float* __restrict__ E,
    const float* __restrict__ coef_t, const float* __restrict__ matsg,
    const float* __restrict__ Wm, const float* __restrict__ T,
    const float* __restrict__ ts, const float* __restrict__ uvgrid,
    const float* __restrict__ Limg, const float* __restrict__ tau,
    const float* __restrict__ alpha, float* __restrict__ out)
{
  // XCD swizzle: bid%8 == y%8 so all 16 batch-groups of a vertex-block land
  // on one XCD (per-XCD D slice = 7 vblocks x 118 x 3KB = 2.5MB < 4MB L2).
  int bid = blockIdx.x;
  int r  = bid & 7;
  int t  = bid >> 3;            // 0..111
  int x  = t & 15;              // batch-group 0..15
  int y  = ((t >> 4) << 3) | r; // vertex-block 0..55
  if (y * VBLK >= NVERT) return;   // uniform early-exit (before barrier)

  __shared__ float clds[KALLOC][NBT];   // 8 KB coef tile
  __shared__ float mlds[NBT][96];       // 6 KB skin mats
  __shared__ float ta_s[NBT], al_s[NBT];

  int tid  = threadIdx.x;
  int lane = tid & 63;
  int wv   = tid >> 6;               // 0..3
  int bbase = x * BBLK;
  int vbase = y * VBLK;
  int v = vbase + wv*64 + lane;
  bool vok = v < NVERT;
  int vc = vok ? v : NVERT - 1;
  int voffi = vc * 3;

  // stage coef: 128 rows x 16 batches = 512 float4, 2 per thread
#pragma unroll
  for (int rep = 0; rep < 2; rep++) {
    int q = tid + rep*256;           // float4 index 0..511
    int row = q >> 2, i4 = q & 3;
    *reinterpret_cast<float4*>(&clds[row][i4*4]) =
        *reinterpret_cast<const float4*>(coef_t + (size_t)row*BATCH + bbase + i4*4);
  }
  // stage mats: 16 x 96 floats = 384 float4
  {
    int q = tid;                     // 0..255
    int bb = q / 24, chunk = q - bb*24;
    *reinterpret_cast<float4*>(&mlds[bb][chunk*4]) =
        *reinterpret_cast<const float4*>(matsg + (size_t)(bbase+bb)*96 + chunk*4);
    q = tid + 256;
    if (q < 384) {
      bb = q / 24; chunk = q - bb*24;
      *reinterpret_cast<float4*>(&mlds[bb][chunk*4]) =
          *reinterpret_cast<const float4*>(matsg + (size_t)(bbase+bb)*96 + chunk*4);
    }
  }
  if (tid < NBT) { ta_s[tid] = tau[bbase+tid]; al_s[tid] = alpha[bbase+tid]; }
  __syncthreads();   // the ONLY barrier

  const float* Pb = P + (size_t)9 * NV3;   // row c<63 -> Pb + c*NV3

  float acc[NBT][3];
#pragma unroll
  for (int j = 0; j < NBT; j++) { acc[j][0]=0.f; acc[j][1]=0.f; acc[j][2]=0.f; }

  // D pipeline: three row-sets -> depth-2 prefetch (coef comes from LDS at use)
  float dA0,dA1,dA2, dB0,dB1,dB2, dC0,dC1,dC2;

#define LOAD_D(cn, D0,D1,D2)                                             \
  {                                                                      \
    int cd = (cn) <= (KTOT-1) ? (cn) : (KTOT-1);                         \
    const float* rp = (cd < KP) ? (Pb + (size_t)cd*NV3)                  \
                                : (E + (size_t)(cd-KP)*NV3);             \
    D0 = rp[voffi+0]; D1 = rp[voffi+1]; D2 = rp[voffi+2];                \
  }

#define FMA_ROW(cn, D0,D1,D2)                                            \
  {                                                                      \
    const float* cp = &clds[(cn)][0];                                    \
    float4 C0 = *reinterpret_cast<const float4*>(cp+0);                  \
    float4 C1 = *reinterpret_cast<const float4*>(cp+4);                  \
    float4 C2 = *reinterpret_cast<const float4*>(cp+8);                  \
    float4 C3 = *reinterpret_cast<const float4*>(cp+12);                 \
    float cf[NBT] = {C0.x,C0.y,C0.z,C0.w, C1.x,C1.y,C1.z,C1.w,           \
                     C2.x,C2.y,C2.z,C2.w, C3.x,C3.y,C3.z,C3.w};          \
    _Pragma("unroll")                                                    \
    for (int j = 0; j < NBT; j++) {                                      \
      acc[j][0] = fmaf(cf[j], D0, acc[j][0]);                            \
      acc[j][1] = fmaf(cf[j], D1, acc[j][1]);                            \
      acc[j][2] = fmaf(cf[j], D2, acc[j][2]);                            \
    }                                                                    \
  }

  LOAD_D(0, dA0,dA1,dA2);
  LOAD_D(1, dB0,dB1,dB2);
  LOAD_D(2, dC0,dC1,dC2);

#pragma unroll 1
  for (int c = 0; c < KPAD; c += 3) {
    FMA_ROW(c+0, dA0,dA1,dA2);  LOAD_D(c+3, dA0,dA1,dA2);
    FMA_ROW(c+1, dB0,dB1,dB2);  LOAD_D(c+4, dB0,dB1,dB2);
    FMA_ROW(c+2, dC0,dC1,dC2);  LOAD_D(c+5, dC0,dC1,dC2);
  }

  // ---------------- fused epilogue (per-vertex lane, 16 batches) ----------
  float W8[NB];
#pragma unroll
  for (int n = 0; n < NB; n++) W8[n] = Wm[(size_t)n*NVERT + vc];
  float T0 = T[vc*3+0], T1 = T[vc*3+1], T2 = T[vc*3+2];
  float s0 = ts[vc*3+0], s1 = ts[vc*3+1], s2 = ts[vc*3+2];
  float u0 = uvgrid[vc*2+0], u1 = uvgrid[vc*2+1];

  float xc = fminf(fmaxf(u0*255.f, 0.f), 255.f);
  float xf = floorf(xc);
  int x0i = (int)xf;
  int x1i = min(x0i+1, 255);
  float wx = xc - xf;

#pragma unroll
  for (int j = 0; j < NBT; j++) {
    float yc = fminf(fmaxf((u1 + ta_s[j])*255.f, 0.f), 255.f);
    float yf = floorf(yc);
    int y0i = (int)yf;
    int y1i = min(y0i+1, 255);
    float wy = yc - yf;
    float v00 = Limg[y0i*256 + x0i], v01 = Limg[y0i*256 + x1i];
    float v10 = Limg[y1i*256 + x0i], v11 = Limg[y1i*256 + x1i];
    float dist = (v00*(1.f-wx) + v01*wx)*(1.f-wy) + (v10*(1.f-wx) + v11*wx)*wy;
    float da = dist * al_s[j];

    float xv0 = acc[j][0] + T0 + da*s0;
    float xv1 = acc[j][1] + T1 + da*s1;
    float xv2 = acc[j][2] + T2 + da*s2;

    float o[3];
#pragma unroll
    for (int i = 0; i < 3; i++) {
      float c0=0.f, c1=0.f, c2=0.f, c3=0.f;
#pragma unroll
      for (int n = 0; n < NB; n++) {
        float4 m = *reinterpret_cast<const float4*>(&mlds[j][n*12 + i*4]);
        float w = W8[n];
        c0 = fmaf(w, m.x, c0); c1 = fmaf(w, m.y, c1);
        c2 = fmaf(w, m.z, c2); c3 = fmaf(w, m.w, c3);
      }
      o[i] = fmaf(c0, xv0, fmaf(c1, xv1, fmaf(c2, xv2, c3)));
    }
    if (vok) {
      size_t off = (size_t)(bbase + j)*NV3 + (size_t)v*3;
      out[off+0] = o[0];
      out[off+1] = o[1];
      out[off+2] = o[2];
    }
  }
}

// ---------------- launcher ----------------
extern "C" void kernel_launch(void* const* d_in, const int* in_sizes, int n_in,
                              void* d_out, int out_size, void* d_ws, size_t ws_size,
                              hipStream_t stream)
{
  const float* theta  = (const float*)d_in[0];
  const float* tau    = (const float*)d_in[1];
  const float* alpha  = (const float*)d_in[2];
  const float* bsw    = (const float*)d_in[3];
  const float* Wm     = (const float*)d_in[4];
  const float* T      = (const float*)d_in[5];
  const float* P      = (const float*)d_in[6];
  const float* L      = (const float*)d_in[7];
  const float* ts     = (const float*)d_in[8];
  const float* L2P    = (const float*)d_in[9];
  const float* E      = (const float*)d_in[10];
  const float* uvgrid = (const float*)d_in[11];
  float* out = (float*)d_out;

  float* coef_t = (float*)d_ws;                     // 128*256 floats
  float* mats   = coef_t + (size_t)KALLOC * BATCH;  // 256*96 floats

  setup_kernel<<<dim3(4), dim3(64), 0, stream>>>(theta, bsw, L2P, coef_t, mats);
  // 896 = 16 batch-groups x 56 vertex-blocks (y=55 exits early)
  fused_kernel<<<dim3(896), dim3(256), 0, stream>>>(
      P, E, coef_t, mats, Wm, T, ts, uvgrid, L, tau, alpha, out);
}